// Round 9
// baseline (153.608 us; speedup 1.0000x reference)
//
#include <hip/hip_runtime.h>
#include <cstdint>
#include <cstddef>

#define NPAIR 9216
#define BSTRIDE 98304   // 1024*96 floats per batch

typedef __attribute__((ext_vector_type(8))) short short8;
typedef __attribute__((ext_vector_type(4))) float f32x4;

__device__ __forceinline__ uint16_t f2bf(float x) {
    uint32_t u = __float_as_uint(x);
    return (uint16_t)((u + 0x7FFF + ((u >> 16) & 1)) >> 16);   // RNE
}
__device__ __forceinline__ float bf2f(uint16_t b) {
    return __uint_as_float(((uint32_t)b) << 16);
}

// ---------------------------------------------------------------------------
// K1 mega-kernel, 256 threads/block, 960 blocks.
// Phase assignment is INTERLEAVED across blockIdx (period-15 pattern:
// 9 Chebyshev : 2 proj+LN : 4 transpose) so in-order dispatch gives every
// CU a proportional mix -> no clumped tail (R8 lesson: segregated ranges
// left 150+ CUs idle while proj/transpose drained on a few).
// ---------------------------------------------------------------------------
union SmemK1 {
    struct { float zb[2][32][100]; float ps[2][32][3][2]; float stats[2][32][2]; } ln; // 27,648 B
    struct { float T[64][65]; } kl;                                                    // 16,640 B
};

__global__ __launch_bounds__(256) void k1_mega(
    const float* __restrict__ x, const float* __restrict__ M,
    const float* __restrict__ P, const float* __restrict__ L,
    const float* __restrict__ gamma, const float* __restrict__ beta,
    float* __restrict__ Z0, float* __restrict__ Z,
    uint16_t* __restrict__ Lt, uint16_t* __restrict__ Wt)
{
    __shared__ SmemK1 sm;
    const int t  = threadIdx.x;
    const int grp = blockIdx.x / 15;     // 64 groups
    const int r   = blockIdx.x % 15;     // 0-8 Cheb, 9-10 proj, 11-14 transpose

    if (r < 9) {
        // ---- basis weights: Chebyshev over s, 64-s chunk per thread ----
        const int cb = grp * 9 + r;              // [0,576)
        const int u  = cb * 256 + t;             // [0, 147456)
        const int p  = u % 9216;                 // row element = j*96 + i
        const int sc = u / 9216;                 // [0,16)
        const int i  = p % 96, j = p / 96;
        const int s0 = sc * 64;
        const int base = (i * 96 + j) * 8;       // period = base + g + 2

        float Pv[8], c[8], cp[8], tc1[8];
        {
            float4 a = *(const float4*)(P + base);
            float4 b = *(const float4*)(P + base + 4);
            Pv[0]=a.x; Pv[1]=a.y; Pv[2]=a.z; Pv[3]=a.w;
            Pv[4]=b.x; Pv[5]=b.y; Pv[6]=b.z; Pv[7]=b.w;
        }
        #pragma unroll
        for (int g = 0; g < 8; ++g) {
            float inv = 1.0f / (float)(base + g + 2);
            float c1  = cospif(2.0f * inv);
            tc1[g] = c1 + c1;
            c[g]  = cospif(2.0f * (float)s0 * inv);
            cp[g] = cospif(2.0f * (float)(s0 - 1) * inv);
        }
        uint16_t* op = Wt + (size_t)s0 * NPAIR + p;
        for (int ss = 0; ss < 64; ++ss) {
            float w = 0.f;
            #pragma unroll
            for (int g = 0; g < 8; ++g) w = fmaf(Pv[g], c[g], w);
            *op = f2bf(w);
            op += NPAIR;
            #pragma unroll
            for (int g = 0; g < 8; ++g) {
                float cn = fmaf(tc1[g], c[g], -cp[g]);
                cp[g] = c[g]; c[g] = cn;
            }
        }
        return;
    }

    if (r < 11) {
        // ---------------- proj + LN (R5/R7-verified structure) ----------------
        const int pb = grp * 2 + (r - 9);        // [0,128)
        const int g = t >> 7, lt = t & 127;
        const int R0 = pb * 64 + g * 32;
        if (lt < 96) {
            float mreg[96];
            #pragma unroll
            for (int k4 = 0; k4 < 24; ++k4) {          // own M row, L1/L2-hot
                float4 v = *(const float4*)(M + lt * 96 + k4 * 4);
                mreg[k4*4+0]=v.x; mreg[k4*4+1]=v.y;
                mreg[k4*4+2]=v.z; mreg[k4*4+3]=v.w;
            }
            for (int rr = 0; rr < 32; ++rr) {
                const float* xr = x + (size_t)(R0 + rr) * 96;  // wave-uniform
                float a0 = 0.f, a1 = 0.f, a2 = 0.f, a3 = 0.f;
                #pragma unroll
                for (int j = 0; j < 96; j += 4) {
                    a0 = fmaf(xr[j+0], mreg[j+0], a0);
                    a1 = fmaf(xr[j+1], mreg[j+1], a1);
                    a2 = fmaf(xr[j+2], mreg[j+2], a2);
                    a3 = fmaf(xr[j+3], mreg[j+3], a3);
                }
                float z = (a0 + a1) + (a2 + a3);
                sm.ln.zb[g][rr][lt] = z;
                Z0[(size_t)(R0 + rr) * 96 + lt] = z;
            }
        }
        __syncthreads();
        if (lt < 96) {                 // segmented sums: 32 rows x 3 segs of 32
            int row = lt / 3, seg = lt % 3;
            const float4* zp = (const float4*)&sm.ln.zb[g][row][seg * 32];
            float s1 = 0.f, s2 = 0.f;
            #pragma unroll
            for (int k = 0; k < 8; ++k) {
                float4 v = zp[k];
                s1 += (v.x + v.y) + (v.z + v.w);
                s2 += (v.x*v.x + v.y*v.y) + (v.z*v.z + v.w*v.w);
            }
            sm.ln.ps[g][row][seg][0] = s1;
            sm.ln.ps[g][row][seg][1] = s2;
        }
        __syncthreads();
        if (lt < 32) {
            float s1 = sm.ln.ps[g][lt][0][0] + sm.ln.ps[g][lt][1][0] + sm.ln.ps[g][lt][2][0];
            float s2 = sm.ln.ps[g][lt][0][1] + sm.ln.ps[g][lt][1][1] + sm.ln.ps[g][lt][2][1];
            float mu  = s1 * (1.f / 96.f);
            float var = s2 * (1.f / 96.f) - mu * mu;
            sm.ln.stats[g][lt][0] = mu;
            sm.ln.stats[g][lt][1] = rsqrtf(var + 1e-5f);
        }
        __syncthreads();
        if (lt < 96) {
            float gm = gamma[lt], bt = beta[lt];
            for (int rr = 0; rr < 32; ++rr) {
                float mu = sm.ln.stats[g][rr][0], rs = sm.ln.stats[g][rr][1];
                Z[(size_t)(R0 + rr) * 96 + lt] = (sm.ln.zb[g][rr][lt] - mu) * rs * gm + bt;
            }
        }
        return;
    }

    // ---------------- Linker transpose: one 64x64 tile per block ----------------
    {
        const int tau = grp * 4 + (r - 11);       // [0,256)
        const int s0 = (tau & 15) * 64, t0 = (tau >> 4) * 64;
        #pragma unroll
        for (int k = 0; k < 16; ++k) {            // coalesced row loads
            int mi = t + 256 * k;
            int sr = mi >> 6, c = mi & 63;
            sm.kl.T[sr][c] = L[(size_t)(s0 + sr) * 1024 + t0 + c];
        }
        __syncthreads();
        {
            const int trow = t >> 2, sc0 = (t & 3) * 16;
            uint32_t w[8];
            #pragma unroll
            for (int q = 0; q < 8; ++q) {
                w[q] = (uint32_t)f2bf(sm.kl.T[sc0 + 2*q][trow]) |
                       ((uint32_t)f2bf(sm.kl.T[sc0 + 2*q + 1][trow]) << 16);
            }
            uint16_t* ob = Lt + (size_t)(t0 + trow) * 1024 + s0 + sc0;
            uint4 o0; o0.x = w[0]; o0.y = w[1]; o0.z = w[2]; o0.w = w[3];
            uint4 o1; o1.x = w[4]; o1.y = w[5]; o1.z = w[6]; o1.w = w[7];
            *(uint4*)ob = o0;
            *(uint4*)(ob + 8) = o1;
        }
    }
}

// ---------------------------------------------------------------------------
// KT: Vt[b][i][s] = bf16( Z0[b,s,i] + sum_j Z[b,s,j]*Wt[s][j*96+i] )
// 1024 blocks x 192 thr (3 full waves): t = g*96+i, g picks b 0-3 / 4-7.
// ---------------------------------------------------------------------------
__global__ __launch_bounds__(192) void kt_apply(
    const float* __restrict__ Z, const float* __restrict__ Z0,
    const uint16_t* __restrict__ Wt, uint16_t* __restrict__ Vt)
{
    const int i  = threadIdx.x % 96;
    const int b0 = (threadIdx.x / 96) * 4;
    const int s  = blockIdx.x;
    float acc[4] = {0.f, 0.f, 0.f, 0.f};
    const uint16_t* wrow = Wt + (size_t)s * NPAIR + i;   // + j*96 per step
    const float* zs = Z + (size_t)b0 * BSTRIDE + (size_t)s * 96;
    #pragma unroll 8
    for (int j = 0; j < 96; ++j) {
        float w = bf2f(wrow[j * 96]);
        #pragma unroll
        for (int bb = 0; bb < 4; ++bb)
            acc[bb] = fmaf(zs[(size_t)bb * BSTRIDE + j], w, acc[bb]);
    }
    #pragma unroll
    for (int bb = 0; bb < 4; ++bb) {
        size_t o = (size_t)(b0 + bb) * BSTRIDE + (size_t)s * 96 + i;
        Vt[((size_t)(b0 + bb) * 96 + i) * 1024 + s] = f2bf(acc[bb] + Z0[o]);
    }
}

// ---------------------------------------------------------------------------
// K3: out[b,t,i] = sum_s Lt[t][s]*Vt[b][i][s]
// MFMA 16x16x32 bf16, K-major operands.  Grid (64,8) x 256 thr:
// one 16-t tile per block, K split x4 across waves, LDS reduce.
// ---------------------------------------------------------------------------
__global__ __launch_bounds__(256) void k3_mfma(
    const uint16_t* __restrict__ Lt, const uint16_t* __restrict__ Vt,
    float* __restrict__ out)
{
    __shared__ float red[4][64][25];     // 25,600 B (+1 pad col)
    const int lane = threadIdx.x & 63;
    const int wv   = threadIdx.x >> 6;   // K chunk [wv*256, +256)
    const int m    = lane & 15;
    const int quad = lane >> 4;
    const int t0   = blockIdx.x * 16;
    const int b    = blockIdx.y;

    const uint16_t* Lp = Lt + (size_t)(t0 + m) * 1024 + wv * 256 + quad * 8;
    const uint16_t* Vp = Vt + ((size_t)b * 96 + m) * 1024 + wv * 256 + quad * 8;

    f32x4 acc[6];
    #pragma unroll
    for (int ii = 0; ii < 6; ++ii) acc[ii] = (f32x4){0.f, 0.f, 0.f, 0.f};

    short8 a = *(const short8*)Lp;
    short8 bv[6];
    #pragma unroll
    for (int ii = 0; ii < 6; ++ii)
        bv[ii] = *(const short8*)(Vp + (size_t)ii * 16 * 1024);

    for (int kc = 0; kc < 7; ++kc) {                 // 8 chunks of K=32
        short8 an = *(const short8*)(Lp + (kc + 1) * 32);
        short8 bn[6];
        #pragma unroll
        for (int ii = 0; ii < 6; ++ii)
            bn[ii] = *(const short8*)(Vp + (size_t)ii * 16 * 1024 + (kc + 1) * 32);
        #pragma unroll
        for (int ii = 0; ii < 6; ++ii)
            acc[ii] = __builtin_amdgcn_mfma_f32_16x16x32_bf16(a, bv[ii], acc[ii], 0, 0, 0);
        a = an;
        #pragma unroll
        for (int ii = 0; ii < 6; ++ii) bv[ii] = bn[ii];
    }
    #pragma unroll
    for (int ii = 0; ii < 6; ++ii)
        acc[ii] = __builtin_amdgcn_mfma_f32_16x16x32_bf16(a, bv[ii], acc[ii], 0, 0, 0);

    #pragma unroll
    for (int ii = 0; ii < 6; ++ii)
        #pragma unroll
        for (int r = 0; r < 4; ++r)
            red[wv][lane][ii * 4 + r] = acc[ii][r];
    __syncthreads();
    {
        const int l2 = threadIdx.x & 63;
        const int ks = (threadIdx.x >> 6) * 6;       // 6 of the 24 k's per thread
        const int m2 = l2 & 15, q2 = l2 >> 4;
        #pragma unroll
        for (int k = ks; k < ks + 6; ++k) {
            float sv = red[0][l2][k] + red[1][l2][k]
                     + red[2][l2][k] + red[3][l2][k];
            int ii = k >> 2, r = k & 3;
            out[(size_t)b * BSTRIDE + (size_t)(t0 + q2 * 4 + r) * 96 + ii * 16 + m2] = sv;
        }
    }
}

extern "C" void kernel_launch(void* const* d_in, const int* in_sizes, int n_in,
                              void* d_out, int out_size, void* d_ws, size_t ws_size,
                              hipStream_t stream)
{
    const float* x     = (const float*)d_in[0];
    const float* M     = (const float*)d_in[1];
    const float* P     = (const float*)d_in[2];
    const float* Lnk   = (const float*)d_in[3];
    const float* gamma = (const float*)d_in[4];
    const float* beta  = (const float*)d_in[5];
    float* out = (float*)d_out;

    uint8_t* ws = (uint8_t*)d_ws;
    uint16_t* Wt = (uint16_t*)ws;                 // 18,874,368 B
    float*    Z0 = (float*)(ws + 18874368);       //  3,145,728 B
    float*    Z  = (float*)(ws + 22020096);       //  3,145,728 B
    uint16_t* Lt = (uint16_t*)(ws + 25165824);    //  2,097,152 B
    uint16_t* Vt = (uint16_t*)(ws + 27262976);    //  1,572,864 B  (~28.8 MB)

    k1_mega <<<960,  256, 0, stream>>>(x, M, P, Lnk, gamma, beta, Z0, Z, Lt, Wt);
    kt_apply<<<1024, 192, 0, stream>>>(Z, Z0, Wt, Vt);
    k3_mfma <<<dim3(64, 8), 256, 0, stream>>>(Lt, Vt, out);
}

// Round 10
// 137.728 us; speedup vs baseline: 1.1153x; 1.1153x over previous
//
#include <hip/hip_runtime.h>
#include <cstdint>
#include <cstddef>

#define NPAIR 9216
#define BSTRIDE 98304   // 1024*96 floats per batch

typedef __attribute__((ext_vector_type(8))) short short8;
typedef __attribute__((ext_vector_type(4))) float f32x4;

__device__ __forceinline__ uint16_t f2bf(float x) {
    uint32_t u = __float_as_uint(x);
    return (uint16_t)((u + 0x7FFF + ((u >> 16) & 1)) >> 16);   // RNE
}
__device__ __forceinline__ float bf2f(uint16_t b) {
    return __uint_as_float(((uint32_t)b) << 16);
}

// ---------------------------------------------------------------------------
// K_CHEB: Wt[s][j*96+i] via Chebyshev cos recurrence.  576 blocks x 256 thr,
// ZERO shared memory -> occupancy limited only by VGPRs (~40) -> 8 waves/SIMD.
// (R6 lesson: merged into the LDS-union mega-kernel this phase ran at ~6
//  wave-slots/CU because every block allocated the 37 KB union.)
// ---------------------------------------------------------------------------
__global__ __launch_bounds__(256) void k_cheb(
    const float* __restrict__ P, uint16_t* __restrict__ Wt)
{
    const int u  = blockIdx.x * 256 + threadIdx.x;  // [0, 147456)
    const int p  = u % 9216;                 // row element = j*96 + i
    const int sc = u / 9216;                 // [0,16)
    const int i  = p % 96, j = p / 96;
    const int s0 = sc * 64;
    const int base = (i * 96 + j) * 8;       // period = base + g + 2

    float Pv[8], c[8], cp[8], tc1[8];
    {
        float4 a = *(const float4*)(P + base);
        float4 b = *(const float4*)(P + base + 4);
        Pv[0]=a.x; Pv[1]=a.y; Pv[2]=a.z; Pv[3]=a.w;
        Pv[4]=b.x; Pv[5]=b.y; Pv[6]=b.z; Pv[7]=b.w;
    }
    #pragma unroll
    for (int g = 0; g < 8; ++g) {
        float inv = 1.0f / (float)(base + g + 2);
        float c1  = cospif(2.0f * inv);
        tc1[g] = c1 + c1;
        c[g]  = cospif(2.0f * (float)s0 * inv);
        cp[g] = cospif(2.0f * (float)(s0 - 1) * inv);
    }
    uint16_t* op = Wt + (size_t)s0 * NPAIR + p;
    for (int ss = 0; ss < 64; ++ss) {
        float w = 0.f;
        #pragma unroll
        for (int g = 0; g < 8; ++g) w = fmaf(Pv[g], c[g], w);
        *op = f2bf(w);
        op += NPAIR;
        #pragma unroll
        for (int g = 0; g < 8; ++g) {
            float cn = fmaf(tc1[g], c[g], -cp[g]);
            cp[g] = c[g]; c[g] = cn;
        }
    }
}

// ---------------------------------------------------------------------------
// K_PT: proj+LN and Linker transpose (R6-verified code), 96 thr, 768 blocks:
//   blocks [0,512):   Z0 = x@M^T + LayerNorm -> Z   (16 rows/block)
//   blocks [512,768): Lt[t][s] = bf16(Linker[s][t]) (64x64 tiles)
// ---------------------------------------------------------------------------
union SmemPT {
    float M[96][97];                                   // 37.2 KB (max)
    struct { float zb[16][100]; float ps[16][6][2]; float stats[16][2]; } ln;
    struct { float T[64][65]; } kl;
};

__global__ __launch_bounds__(96) void k_pt(
    const float* __restrict__ x, const float* __restrict__ M,
    const float* __restrict__ L,
    const float* __restrict__ gamma, const float* __restrict__ beta,
    float* __restrict__ Z0, float* __restrict__ Z,
    uint16_t* __restrict__ Lt)
{
    __shared__ SmemPT sm;
    const int t  = threadIdx.x;
    const int bx = blockIdx.x;

    if (bx < 512) {
        // ---------------- proj + LN ----------------
        const int R0 = bx * 16;
        for (int k = 0; k < 24; ++k) {
            int mm = t + 96 * k;
            int i = mm / 24, j0 = (mm % 24) * 4;
            float4 v = *(const float4*)(M + i * 96 + j0);
            sm.M[i][j0]   = v.x; sm.M[i][j0+1] = v.y;
            sm.M[i][j0+2] = v.z; sm.M[i][j0+3] = v.w;
        }
        __syncthreads();
        float mreg[96];
        #pragma unroll
        for (int j = 0; j < 96; ++j) mreg[j] = sm.M[t][j];
        __syncthreads();   // M region dead; ln region reuses it

        for (int r = 0; r < 16; ++r) {
            const float* xr = x + (size_t)(R0 + r) * 96;  // wave-uniform
            float a0 = 0.f, a1 = 0.f, a2 = 0.f, a3 = 0.f;
            #pragma unroll
            for (int j = 0; j < 96; j += 4) {
                a0 = fmaf(xr[j+0], mreg[j+0], a0);
                a1 = fmaf(xr[j+1], mreg[j+1], a1);
                a2 = fmaf(xr[j+2], mreg[j+2], a2);
                a3 = fmaf(xr[j+3], mreg[j+3], a3);
            }
            float z = (a0 + a1) + (a2 + a3);
            sm.ln.zb[r][t] = z;
            Z0[(size_t)(R0 + r) * 96 + t] = z;
        }
        __syncthreads();
        {
            const int row = t / 6, seg = t % 6;
            const float4* zp = (const float4*)&sm.ln.zb[row][seg * 16];
            float s1 = 0.f, s2 = 0.f;
            #pragma unroll
            for (int k = 0; k < 4; ++k) {
                float4 v = zp[k];
                s1 += v.x + v.y + v.z + v.w;
                s2 += v.x*v.x + v.y*v.y + v.z*v.z + v.w*v.w;
            }
            sm.ln.ps[row][seg][0] = s1;
            sm.ln.ps[row][seg][1] = s2;
        }
        __syncthreads();
        if (t < 16) {
            float s1 = 0.f, s2 = 0.f;
            #pragma unroll
            for (int k = 0; k < 6; ++k) {
                s1 += sm.ln.ps[t][k][0];
                s2 += sm.ln.ps[t][k][1];
            }
            float mu  = s1 * (1.f / 96.f);
            float var = s2 * (1.f / 96.f) - mu * mu;
            sm.ln.stats[t][0] = mu;
            sm.ln.stats[t][1] = rsqrtf(var + 1e-5f);
        }
        __syncthreads();
        {
            float gm = gamma[t], bt = beta[t];
            for (int r = 0; r < 16; ++r) {
                float mu = sm.ln.stats[r][0], rs = sm.ln.stats[r][1];
                Z[(size_t)(R0 + r) * 96 + t] =
                    (sm.ln.zb[r][t] - mu) * rs * gm + bt;
            }
        }
        return;
    }

    // ---------------- Linker transpose -> bf16 ----------------
    {
        const int bx2 = bx - 512;
        const int s0 = (bx2 & 15) * 64, t0 = (bx2 >> 4) * 64;
        if (t < 64) {
            for (int r = 0; r < 64; ++r)
                sm.kl.T[r][t] = L[(size_t)(s0 + r) * 1024 + t0 + t];
        }
        __syncthreads();
        if (t < 64) {
            uint16_t* orow = Lt + (size_t)(t0 + t) * 1024 + s0;
            #pragma unroll
            for (int c4 = 0; c4 < 16; ++c4) {
                uint32_t u01 = (uint32_t)f2bf(sm.kl.T[c4*4+0][t]) |
                               ((uint32_t)f2bf(sm.kl.T[c4*4+1][t]) << 16);
                uint32_t u23 = (uint32_t)f2bf(sm.kl.T[c4*4+2][t]) |
                               ((uint32_t)f2bf(sm.kl.T[c4*4+3][t]) << 16);
                uint2 o; o.x = u01; o.y = u23;
                *(uint2*)(orow + c4 * 4) = o;
            }
        }
    }
}

// ---------------------------------------------------------------------------
// KT: Vt[b][i][s] = bf16( Z0[b,s,i] + sum_j Z[b,s,j]*Wt[s][j*96+i] )
// One block per s; lane = i (R6-verified).
// ---------------------------------------------------------------------------
__global__ __launch_bounds__(96) void kt_apply(
    const float* __restrict__ Z, const float* __restrict__ Z0,
    const uint16_t* __restrict__ Wt, uint16_t* __restrict__ Vt)
{
    const int i = threadIdx.x;
    const int s = blockIdx.x;
    float acc[8] = {0.f,0.f,0.f,0.f,0.f,0.f,0.f,0.f};
    const uint16_t* wrow = Wt + (size_t)s * NPAIR + i;   // + j*96 per step
    const float* zs = Z + (size_t)s * 96;                // wave-uniform base
    #pragma unroll 8
    for (int j = 0; j < 96; ++j) {
        float w = bf2f(wrow[j * 96]);
        #pragma unroll
        for (int bb = 0; bb < 8; ++bb)
            acc[bb] = fmaf(zs[(size_t)bb * BSTRIDE + j], w, acc[bb]);
    }
    #pragma unroll
    for (int bb = 0; bb < 8; ++bb) {
        size_t o = (size_t)bb * BSTRIDE + (size_t)s * 96 + i;
        Vt[((size_t)bb * 96 + i) * 1024 + s] = f2bf(acc[bb] + Z0[o]);
    }
}

// ---------------------------------------------------------------------------
// K3: out[b,t,i] = sum_{s=0..1023} Lt[t][s]*Vt[b][i][s]
// MFMA 16x16x32 bf16, K-major operands, full K per wave (R6-verified).
// 128 thr (2 waves, t-tile 32), grid (32, 8).  Depth-2 pipeline.
// ---------------------------------------------------------------------------
__global__ __launch_bounds__(128) void k3_mfma(
    const uint16_t* __restrict__ Lt, const uint16_t* __restrict__ Vt,
    float* __restrict__ out)
{
    const int lane = threadIdx.x & 63;
    const int wv   = threadIdx.x >> 6;
    const int m    = lane & 15;
    const int quad = lane >> 4;
    const int t0   = blockIdx.x * 32 + wv * 16;
    const int b    = blockIdx.y;

    const uint16_t* Lp = Lt + (size_t)(t0 + m) * 1024 + quad * 8;
    const uint16_t* Vp = Vt + ((size_t)b * 96 + m) * 1024 + quad * 8;

    f32x4 acc[6];
    #pragma unroll
    for (int ii = 0; ii < 6; ++ii) acc[ii] = (f32x4){0.f, 0.f, 0.f, 0.f};

    short8 a = *(const short8*)Lp;
    short8 bv[6];
    #pragma unroll
    for (int ii = 0; ii < 6; ++ii)
        bv[ii] = *(const short8*)(Vp + (size_t)ii * 16 * 1024);

    for (int kc = 0; kc < 31; ++kc) {
        short8 an = *(const short8*)(Lp + (kc + 1) * 32);
        short8 bn[6];
        #pragma unroll
        for (int ii = 0; ii < 6; ++ii)
            bn[ii] = *(const short8*)(Vp + (size_t)ii * 16 * 1024 + (kc + 1) * 32);
        #pragma unroll
        for (int ii = 0; ii < 6; ++ii)
            acc[ii] = __builtin_amdgcn_mfma_f32_16x16x32_bf16(a, bv[ii], acc[ii], 0, 0, 0);
        a = an;
        #pragma unroll
        for (int ii = 0; ii < 6; ++ii) bv[ii] = bn[ii];
    }
    #pragma unroll
    for (int ii = 0; ii < 6; ++ii)
        acc[ii] = __builtin_amdgcn_mfma_f32_16x16x32_bf16(a, bv[ii], acc[ii], 0, 0, 0);

    float* po = out + (size_t)b * BSTRIDE;
    #pragma unroll
    for (int ii = 0; ii < 6; ++ii)
        #pragma unroll
        for (int r = 0; r < 4; ++r)
            po[(size_t)(t0 + quad * 4 + r) * 96 + ii * 16 + m] = acc[ii][r];
}

extern "C" void kernel_launch(void* const* d_in, const int* in_sizes, int n_in,
                              void* d_out, int out_size, void* d_ws, size_t ws_size,
                              hipStream_t stream)
{
    const float* x     = (const float*)d_in[0];
    const float* M     = (const float*)d_in[1];
    const float* P     = (const float*)d_in[2];
    const float* Lnk   = (const float*)d_in[3];
    const float* gamma = (const float*)d_in[4];
    const float* beta  = (const float*)d_in[5];
    float* out = (float*)d_out;

    uint8_t* ws = (uint8_t*)d_ws;
    uint16_t* Wt = (uint16_t*)ws;                 // 18,874,368 B
    float*    Z0 = (float*)(ws + 18874368);       //  3,145,728 B
    float*    Z  = (float*)(ws + 22020096);       //  3,145,728 B
    uint16_t* Lt = (uint16_t*)(ws + 25165824);    //  2,097,152 B
    uint16_t* Vt = (uint16_t*)(ws + 27262976);    //  1,572,864 B  (~28.8 MB)

    k_cheb  <<<576,  256, 0, stream>>>(P, Wt);
    k_pt    <<<768,  96,  0, stream>>>(x, M, Lnk, gamma, beta, Z0, Z, Lt);
    kt_apply<<<1024, 96,  0, stream>>>(Z, Z0, Wt, Vt);
    k3_mfma <<<dim3(32, 8), 128, 0, stream>>>(Lt, Vt, out);
}

// Round 11
// 129.371 us; speedup vs baseline: 1.1873x; 1.0646x over previous
//
#include <hip/hip_runtime.h>
#include <cstdint>
#include <cstddef>

#define NPAIR 9216
#define BSTRIDE 98304   // 1024*96 floats per batch

typedef __attribute__((ext_vector_type(8))) short short8;
typedef __attribute__((ext_vector_type(4))) float f32x4;

__device__ __forceinline__ uint16_t f2bf(float x) {
    uint32_t u = __float_as_uint(x);
    return (uint16_t)((u + 0x7FFF + ((u >> 16) & 1)) >> 16);   // RNE
}
__device__ __forceinline__ float bf2f(uint16_t b) {
    return __uint_as_float(((uint32_t)b) << 16);
}

// ---------------------------------------------------------------------------
// K1 mega-kernel, 96 threads/block, 3840 blocks (R6-proven structure):
//   blocks [0,512):    Z0 = x@M^T + fused LayerNorm -> Z   (16 rows/block)
//   blocks [512,768):  Lt[t][s] = bf16(Linker[s][t])       (64x64 tiles)
//   blocks [768,3840): Wt[s][j*96+i] via Chebyshev cos recurrence
//                      (s-chunk 32: 2x wave parallelism vs R6's 64)
// ---------------------------------------------------------------------------
union SmemK1 {
    float M[96][97];                                   // 37.2 KB (max)
    struct { float zb[16][100]; float ps[16][6][2]; float stats[16][2]; } ln;
    struct { float T[64][65]; } kl;
};

__global__ __launch_bounds__(96) void k1_mega(
    const float* __restrict__ x, const float* __restrict__ M,
    const float* __restrict__ P, const float* __restrict__ L,
    const float* __restrict__ gamma, const float* __restrict__ beta,
    float* __restrict__ Z0, float* __restrict__ Z,
    uint16_t* __restrict__ Lt, uint16_t* __restrict__ Wt)
{
    __shared__ SmemK1 sm;
    const int t  = threadIdx.x;
    const int bx = blockIdx.x;

    if (bx < 512) {
        // ---------------- proj + LN ----------------
        const int R0 = bx * 16;
        for (int k = 0; k < 24; ++k) {
            int mm = t + 96 * k;
            int i = mm / 24, j0 = (mm % 24) * 4;
            float4 v = *(const float4*)(M + i * 96 + j0);
            sm.M[i][j0]   = v.x; sm.M[i][j0+1] = v.y;
            sm.M[i][j0+2] = v.z; sm.M[i][j0+3] = v.w;
        }
        __syncthreads();
        float mreg[96];
        #pragma unroll
        for (int j = 0; j < 96; ++j) mreg[j] = sm.M[t][j];
        __syncthreads();   // M region dead; ln region reuses it

        for (int r = 0; r < 16; ++r) {
            const float* xr = x + (size_t)(R0 + r) * 96;  // wave-uniform
            float a0 = 0.f, a1 = 0.f, a2 = 0.f, a3 = 0.f;
            #pragma unroll
            for (int j = 0; j < 96; j += 4) {
                a0 = fmaf(xr[j+0], mreg[j+0], a0);
                a1 = fmaf(xr[j+1], mreg[j+1], a1);
                a2 = fmaf(xr[j+2], mreg[j+2], a2);
                a3 = fmaf(xr[j+3], mreg[j+3], a3);
            }
            float z = (a0 + a1) + (a2 + a3);
            sm.ln.zb[r][t] = z;
            Z0[(size_t)(R0 + r) * 96 + t] = z;
        }
        __syncthreads();
        {
            const int row = t / 6, seg = t % 6;
            const float4* zp = (const float4*)&sm.ln.zb[row][seg * 16];
            float s1 = 0.f, s2 = 0.f;
            #pragma unroll
            for (int k = 0; k < 4; ++k) {
                float4 v = zp[k];
                s1 += v.x + v.y + v.z + v.w;
                s2 += v.x*v.x + v.y*v.y + v.z*v.z + v.w*v.w;
            }
            sm.ln.ps[row][seg][0] = s1;
            sm.ln.ps[row][seg][1] = s2;
        }
        __syncthreads();
        if (t < 16) {
            float s1 = 0.f, s2 = 0.f;
            #pragma unroll
            for (int k = 0; k < 6; ++k) {
                s1 += sm.ln.ps[t][k][0];
                s2 += sm.ln.ps[t][k][1];
            }
            float mu  = s1 * (1.f / 96.f);
            float var = s2 * (1.f / 96.f) - mu * mu;
            sm.ln.stats[t][0] = mu;
            sm.ln.stats[t][1] = rsqrtf(var + 1e-5f);
        }
        __syncthreads();
        {
            float gm = gamma[t], bt = beta[t];
            for (int r = 0; r < 16; ++r) {
                float mu = sm.ln.stats[r][0], rs = sm.ln.stats[r][1];
                Z[(size_t)(R0 + r) * 96 + t] =
                    (sm.ln.zb[r][t] - mu) * rs * gm + bt;
            }
        }
        return;
    }

    if (bx < 768) {
        // ---------------- Linker transpose -> bf16 ----------------
        const int bx2 = bx - 512;
        const int s0 = (bx2 & 15) * 64, t0 = (bx2 >> 4) * 64;
        if (t < 64) {
            for (int r = 0; r < 64; ++r)
                sm.kl.T[r][t] = L[(size_t)(s0 + r) * 1024 + t0 + t];
        }
        __syncthreads();
        if (t < 64) {
            uint16_t* orow = Lt + (size_t)(t0 + t) * 1024 + s0;
            #pragma unroll
            for (int c4 = 0; c4 < 16; ++c4) {
                uint32_t u01 = (uint32_t)f2bf(sm.kl.T[c4*4+0][t]) |
                               ((uint32_t)f2bf(sm.kl.T[c4*4+1][t]) << 16);
                uint32_t u23 = (uint32_t)f2bf(sm.kl.T[c4*4+2][t]) |
                               ((uint32_t)f2bf(sm.kl.T[c4*4+3][t]) << 16);
                uint2 o; o.x = u01; o.y = u23;
                *(uint2*)(orow + c4 * 4) = o;
            }
        }
        return;
    }

    // ---------------- basis weights (Chebyshev over s) ----------------
    // element p = j*96 + i within row s; period base = (i*96+j)*8;
    // 32-s chunk per thread (2x more waves than R6's 64-s chunks)
    {
        const int idx = bx - 768;          // [0,3072)
        const int pb  = idx % 96;
        const int sc  = idx / 96;          // [0,32)
        const int p   = pb * 96 + t;       // element index in row = j*96+i
        const int i   = p % 96, j = p / 96;
        const int s0  = sc * 32;
        const int base = (i * 96 + j) * 8; // period = base + g + 2

        float Pv[8], c[8], cp[8], tc1[8];
        {
            float4 a = *(const float4*)(P + base);
            float4 b = *(const float4*)(P + base + 4);
            Pv[0]=a.x; Pv[1]=a.y; Pv[2]=a.z; Pv[3]=a.w;
            Pv[4]=b.x; Pv[5]=b.y; Pv[6]=b.z; Pv[7]=b.w;
        }
        #pragma unroll
        for (int g = 0; g < 8; ++g) {
            float inv = 1.0f / (float)(base + g + 2);
            float c1  = cospif(2.0f * inv);
            tc1[g] = c1 + c1;
            c[g]  = cospif(2.0f * (float)s0 * inv);
            cp[g] = cospif(2.0f * (float)(s0 - 1) * inv);
        }
        uint16_t* op = Wt + (size_t)s0 * NPAIR + p;
        #pragma unroll 4
        for (int ss = 0; ss < 32; ++ss) {
            float w = 0.f;
            #pragma unroll
            for (int g = 0; g < 8; ++g) w = fmaf(Pv[g], c[g], w);
            *op = f2bf(w);
            op += NPAIR;
            #pragma unroll
            for (int g = 0; g < 8; ++g) {
                float cn = fmaf(tc1[g], c[g], -cp[g]);
                cp[g] = c[g]; c[g] = cn;
            }
        }
    }
}

// ---------------------------------------------------------------------------
// KT: Vt[b][i][s] = bf16( Z0[b,s,i] + sum_j Z[b,s,j]*Wt[s][j*96+i] )
// 512 blocks x 192 thr: i = t%96, b-group = t/96 (b 0-3 / 4-7), TWO s per
// block.  Packs the two s-adjacent bf16 into ONE dword store -> halves the
// Vt scatter instruction count and doubles write granularity (R10 lesson:
// 2B x 64-line scatter causes cross-XCD partial-line RMW amplification).
// ---------------------------------------------------------------------------
__global__ __launch_bounds__(192) void kt_apply(
    const float* __restrict__ Z, const float* __restrict__ Z0,
    const uint16_t* __restrict__ Wt, uint16_t* __restrict__ Vt)
{
    const int i  = threadIdx.x % 96;
    const int b0 = (threadIdx.x / 96) * 4;
    const int s0 = blockIdx.x * 2;
    float acc0[4] = {0.f, 0.f, 0.f, 0.f};
    float acc1[4] = {0.f, 0.f, 0.f, 0.f};
    const uint16_t* w0 = Wt + (size_t)s0 * NPAIR + i;   // + j*96 per step
    const uint16_t* w1 = w0 + NPAIR;
    const float* z0p = Z + (size_t)b0 * BSTRIDE + (size_t)s0 * 96;
    const float* z1p = z0p + 96;
    #pragma unroll 4
    for (int j = 0; j < 96; ++j) {
        float wa = bf2f(w0[j * 96]);
        float wb = bf2f(w1[j * 96]);
        #pragma unroll
        for (int bb = 0; bb < 4; ++bb) {
            acc0[bb] = fmaf(z0p[(size_t)bb * BSTRIDE + j], wa, acc0[bb]);
            acc1[bb] = fmaf(z1p[(size_t)bb * BSTRIDE + j], wb, acc1[bb]);
        }
    }
    #pragma unroll
    for (int bb = 0; bb < 4; ++bb) {
        const int b = b0 + bb;
        size_t o0 = (size_t)b * BSTRIDE + (size_t)s0 * 96 + i;
        uint32_t lo = f2bf(acc0[bb] + Z0[o0]);
        uint32_t hi = f2bf(acc1[bb] + Z0[o0 + 96]);
        *(uint32_t*)(Vt + ((size_t)b * 96 + i) * 1024 + s0) = lo | (hi << 16);
    }
}

// ---------------------------------------------------------------------------
// K3: out[b,t,i] = sum_{s=0..1023} Lt[t][s]*Vt[b][i][s]
// MFMA 16x16x32 bf16, K-major operands, full K per wave (R6-verified).
// 128 thr (2 waves, t-tile 32), grid (32, 8).  Depth-2 pipeline.
// ---------------------------------------------------------------------------
__global__ __launch_bounds__(128) void k3_mfma(
    const uint16_t* __restrict__ Lt, const uint16_t* __restrict__ Vt,
    float* __restrict__ out)
{
    const int lane = threadIdx.x & 63;
    const int wv   = threadIdx.x >> 6;
    const int m    = lane & 15;
    const int quad = lane >> 4;
    const int t0   = blockIdx.x * 32 + wv * 16;
    const int b    = blockIdx.y;

    const uint16_t* Lp = Lt + (size_t)(t0 + m) * 1024 + quad * 8;
    const uint16_t* Vp = Vt + ((size_t)b * 96 + m) * 1024 + quad * 8;

    f32x4 acc[6];
    #pragma unroll
    for (int ii = 0; ii < 6; ++ii) acc[ii] = (f32x4){0.f, 0.f, 0.f, 0.f};

    short8 a = *(const short8*)Lp;
    short8 bv[6];
    #pragma unroll
    for (int ii = 0; ii < 6; ++ii)
        bv[ii] = *(const short8*)(Vp + (size_t)ii * 16 * 1024);

    for (int kc = 0; kc < 31; ++kc) {
        short8 an = *(const short8*)(Lp + (kc + 1) * 32);
        short8 bn[6];
        #pragma unroll
        for (int ii = 0; ii < 6; ++ii)
            bn[ii] = *(const short8*)(Vp + (size_t)ii * 16 * 1024 + (kc + 1) * 32);
        #pragma unroll
        for (int ii = 0; ii < 6; ++ii)
            acc[ii] = __builtin_amdgcn_mfma_f32_16x16x32_bf16(a, bv[ii], acc[ii], 0, 0, 0);
        a = an;
        #pragma unroll
        for (int ii = 0; ii < 6; ++ii) bv[ii] = bn[ii];
    }
    #pragma unroll
    for (int ii = 0; ii < 6; ++ii)
        acc[ii] = __builtin_amdgcn_mfma_f32_16x16x32_bf16(a, bv[ii], acc[ii], 0, 0, 0);

    float* po = out + (size_t)b * BSTRIDE;
    #pragma unroll
    for (int ii = 0; ii < 6; ++ii)
        #pragma unroll
        for (int r = 0; r < 4; ++r)
            po[(size_t)(t0 + quad * 4 + r) * 96 + ii * 16 + m] = acc[ii][r];
}

extern "C" void kernel_launch(void* const* d_in, const int* in_sizes, int n_in,
                              void* d_out, int out_size, void* d_ws, size_t ws_size,
                              hipStream_t stream)
{
    const float* x     = (const float*)d_in[0];
    const float* M     = (const float*)d_in[1];
    const float* P     = (const float*)d_in[2];
    const float* Lnk   = (const float*)d_in[3];
    const float* gamma = (const float*)d_in[4];
    const float* beta  = (const float*)d_in[5];
    float* out = (float*)d_out;

    uint8_t* ws = (uint8_t*)d_ws;
    uint16_t* Wt = (uint16_t*)ws;                 // 18,874,368 B
    float*    Z0 = (float*)(ws + 18874368);       //  3,145,728 B
    float*    Z  = (float*)(ws + 22020096);       //  3,145,728 B
    uint16_t* Lt = (uint16_t*)(ws + 25165824);    //  2,097,152 B
    uint16_t* Vt = (uint16_t*)(ws + 27262976);    //  1,572,864 B  (~28.8 MB)

    k1_mega <<<3840, 96, 0, stream>>>(x, M, P, Lnk, gamma, beta, Z0, Z, Lt, Wt);
    kt_apply<<<512, 192, 0, stream>>>(Z, Z0, Wt, Vt);
    k3_mfma <<<dim3(32, 8), 128, 0, stream>>>(Lt, Vt, out);
}